// Round 8
// baseline (260.101 us; speedup 1.0000x reference)
//
#include <hip/hip_runtime.h>
#include <cstdint>
#include <cstddef>

typedef unsigned short u16;
typedef unsigned int u32;
typedef __attribute__((ext_vector_type(8))) short short8;
typedef __attribute__((ext_vector_type(4))) float f32x4;

__device__ __forceinline__ float bf2f(u16 v) { return __uint_as_float((u32)v << 16); }
__device__ __forceinline__ u16 f2bf(float f) {
    u32 u = __float_as_uint(f);
    u = (u + 0x7fffu + ((u >> 16) & 1u)) >> 16;   // RNE, finite values only
    return (u16)u;
}

// async global->LDS, 16 B/lane; LDS dest must be wave-uniform base + lane*16
#define GLD16(g, l) __builtin_amdgcn_global_load_lds( \
    (const __attribute__((address_space(1))) void*)(g), \
    (__attribute__((address_space(3))) void*)(l), 16, 0, 0)

// ------------------------------------------------------------------
// Per-block dtype sniff (flag=1 -> fp32 inputs). Wave-uniform ballots.
// ------------------------------------------------------------------
__device__ __forceinline__ int sniff_fp(const void* x) {
    const u16* xs = (const u16*)x;
    const int lane = threadIdx.x & 63;
    int cnt = 0;
    #pragma unroll
    for (int k = 0; k < 4; ++k) {
        const int i = lane * 4 + k;                // i in 0..255, each once
        const int e = (xs[2 * i] >> 7) & 0xFF;
        cnt += (int)__popcll(__ballot(e >= 96 && e <= 135));
    }
    return (cnt < 128) ? 1 : 0;
}

// ------------------------------------------------------------------
// Kernel 1 (prep): fused W-convert + x_j stencil, self-detecting.
// grid (50, 16): cg 0..47 = xj blocks, cg 48..49 = W conversion.
// xc layout: [b][group 0..95][hw][8c]; groups 0..47 = x, 48..95 = x_j.
// (unchanged from r5/r7 — passed at ~<91 us; counters expected next round)
// ------------------------------------------------------------------
__global__ __launch_bounds__(512) void prep_kernel(const void* __restrict__ xin,
                                                   const void* __restrict__ w,
                                                   u16* __restrict__ xc,
                                                   u16* __restrict__ wbf) {
    const int cg = blockIdx.x, b = blockIdx.y;
    const int fp = sniff_fp(xin);

    if (cg >= 48) {
        const int base = ((cg - 48) * 16 + b) * 512 + threadIdx.x;
        for (int i = base; i < 384 * 768; i += 32 * 512) {
            if (fp) wbf[i] = f2bf(((const float*)w)[i]);
            else    wbf[i] = ((const u16*)w)[i];
        }
        return;
    }

    __shared__ __align__(16) u16 pl[3136][8];
    const size_t plane0 = ((size_t)b * 384 + (size_t)cg * 8) * 3136;

    if (fp) {
        const float* xb = (const float*)xin + plane0;
        for (int g = threadIdx.x; g < 784; g += 512) {
            const int p = g * 4;
            float vv[8][4];
            #pragma unroll
            for (int c = 0; c < 8; ++c) {
                const float4 t = *(const float4*)(xb + (size_t)c * 3136 + p);
                vv[c][0] = t.x; vv[c][1] = t.y; vv[c][2] = t.z; vv[c][3] = t.w;
            }
            #pragma unroll
            for (int i = 0; i < 4; ++i) {
                u32 q[4];
                #pragma unroll
                for (int cc = 0; cc < 4; ++cc)
                    q[cc] = (u32)f2bf(vv[cc * 2][i]) | ((u32)f2bf(vv[cc * 2 + 1][i]) << 16);
                *(uint4*)&pl[p + i][0] = make_uint4(q[0], q[1], q[2], q[3]);
            }
        }
    } else {
        const u16* xb = (const u16*)xin + plane0;
        for (int g = threadIdx.x; g < 784; g += 512) {
            const int p = g * 4;
            u32 rc[8][2];
            #pragma unroll
            for (int c = 0; c < 8; ++c) {
                const uint2 t = *(const uint2*)(xb + (size_t)c * 3136 + p);
                rc[c][0] = t.x; rc[c][1] = t.y;
            }
            #pragma unroll
            for (int i = 0; i < 4; ++i) {
                const int d = i >> 1, sh = (i & 1) * 16;
                u32 q[4];
                #pragma unroll
                for (int cc = 0; cc < 4; ++cc) {
                    const u32 lo = (rc[cc * 2][d] >> sh) & 0xFFFFu;
                    const u32 hi = (rc[cc * 2 + 1][d] >> sh) & 0xFFFFu;
                    q[cc] = lo | (hi << 16);
                }
                *(uint4*)&pl[p + i][0] = make_uint4(q[0], q[1], q[2], q[3]);
            }
        }
    }
    __syncthreads();

    for (int p = threadIdx.x; p < 3136; p += 512) {
        const int h = p / 56, w2 = p - h * 56;
        const uint4 self = *(const uint4*)&pl[p][0];
        const u32 sw[4] = {self.x, self.y, self.z, self.w};
        float xv[8], mn[8];
        #pragma unroll
        for (int c2 = 0; c2 < 4; ++c2) {
            xv[c2 * 2]     = __uint_as_float(sw[c2] << 16);
            xv[c2 * 2 + 1] = __uint_as_float(sw[c2] & 0xFFFF0000u);
            mn[c2 * 2] = xv[c2 * 2]; mn[c2 * 2 + 1] = xv[c2 * 2 + 1];
        }
        const int S[5] = {1, 3, 7, 15, 31};
        #pragma unroll
        for (int si = 0; si < 5; ++si) {
            const int s = S[si];
            int hp = h + s; if (hp >= 56) hp -= 56;
            int hm = h - s; if (hm < 0)   hm += 56;
            int wp = w2 + s; if (wp >= 56) wp -= 56;
            int wm = w2 - s; if (wm < 0)   wm += 56;
            const uint4 n0 = *(const uint4*)&pl[hp * 56 + w2][0];
            const uint4 n1 = *(const uint4*)&pl[hm * 56 + w2][0];
            const uint4 n2 = *(const uint4*)&pl[h * 56 + wp][0];
            const uint4 n3 = *(const uint4*)&pl[h * 56 + wm][0];
            const u32 w0[4] = {n0.x, n0.y, n0.z, n0.w};
            const u32 w1[4] = {n1.x, n1.y, n1.z, n1.w};
            const u32 wA[4] = {n2.x, n2.y, n2.z, n2.w};
            const u32 wB[4] = {n3.x, n3.y, n3.z, n3.w};
            #pragma unroll
            for (int c2 = 0; c2 < 4; ++c2) {
                mn[c2 * 2] = fminf(
                    fminf(__uint_as_float(w0[c2] << 16), __uint_as_float(w1[c2] << 16)),
                    fminf(fminf(__uint_as_float(wA[c2] << 16), __uint_as_float(wB[c2] << 16)),
                          mn[c2 * 2]));
                mn[c2 * 2 + 1] = fminf(
                    fminf(__uint_as_float(w0[c2] & 0xFFFF0000u), __uint_as_float(w1[c2] & 0xFFFF0000u)),
                    fminf(fminf(__uint_as_float(wA[c2] & 0xFFFF0000u), __uint_as_float(wB[c2] & 0xFFFF0000u)),
                          mn[c2 * 2 + 1]));
            }
        }
        u32 jq[4];
        #pragma unroll
        for (int c2 = 0; c2 < 4; ++c2)
            jq[c2] = (u32)f2bf(xv[c2 * 2] - mn[c2 * 2]) |
                     ((u32)f2bf(xv[c2 * 2 + 1] - mn[c2 * 2 + 1]) << 16);
        u16* px = xc + ((((size_t)b * 96) + cg) * 3136 + p) * 8;
        u16* pj = xc + ((((size_t)b * 96) + 48 + cg) * 3136 + p) * 8;
        *(uint4*)px = self;
        *(uint4*)pj = make_uint4(jq[0], jq[1], jq[2], jq[3]);
    }
}

// ------------------------------------------------------------------
// Kernel 2 (gemm): Y = Wbf[384,768] @ Xc[768,50176] + BN + exact GELU.
// v8 = v7 tile/compute/epilogue UNCHANGED; sync pattern replaced with
// counted-vmcnt distance-2 prefetch (T3/T4):
//   3 staging buffers (3 x 8 KB), STAGE(q+2) issued 2 phases ahead;
//   per phase: [STAGE(q+2); s_waitcnt vmcnt(4); s_barrier; COMPUTE(q);
//   s_barrier]. vmcnt(4) retires exactly st(q) while st(q+1), st(q+2)
//   stay in flight ACROSS the barrier (v7's __syncthreads drained
//   vmcnt to 0 every phase -> measured 62% stall).
// Hazard audit: STAGE(q+2) writes buf[(q+2)%3], last read by
// COMPUTE(q-1); all waves exited that read at the preceding barrier.
// Tile M=192 x N=64; 4 waves, 3x4 frags of mfma 16x16x32; 12 phases
// of K=64. grid (784, 2), block 256. Self-detecting.
// ------------------------------------------------------------------
__global__ __launch_bounds__(256) void gemm_kernel(
        const u16* __restrict__ xc, const u16* __restrict__ Wt,
        const void* __restrict__ cb, const void* __restrict__ bsc,
        const void* __restrict__ bbi, const void* __restrict__ bme,
        const void* __restrict__ bva, void* __restrict__ outp,
        const void* __restrict__ x0) {
    const int ntile = blockIdx.x;             // 0..783
    const int mtile = blockIdx.y;             // 0..1
    const int fp = sniff_fp(x0);
    // smem: 3 x 8 KB B ring (24576 B), reused in epilogue as
    // 4 waves x 16x68 f32 transpose tiles (17408 B). PB separate.
    __shared__ __align__(16) unsigned char smem[24576];
    __shared__ float2 PB[192];
    u16* const Bsu = (u16*)smem;

    const int tid = threadIdx.x;
    if (tid < 192) {
        const int o = mtile * 192 + tid;
        float vsc, vva, vcb, vme, vbi;
        if (fp) {
            vsc = ((const float*)bsc)[o]; vva = ((const float*)bva)[o];
            vcb = ((const float*)cb)[o];  vme = ((const float*)bme)[o];
            vbi = ((const float*)bbi)[o];
        } else {
            vsc = bf2f(((const u16*)bsc)[o]); vva = bf2f(((const u16*)bva)[o]);
            vcb = bf2f(((const u16*)cb)[o]);  vme = bf2f(((const u16*)bme)[o]);
            vbi = bf2f(((const u16*)bbi)[o]);
        }
        const float seff = vsc * rsqrtf(vva + 1e-5f);
        PB[tid] = make_float2(seff, (vcb - vme) * seff + vbi);
    }

    const int lane = tid & 63, wv = tid >> 6;
    const int quad = lane >> 4, l16 = lane & 15;
    const int bb  = ntile / 49;
    const int hw0 = (ntile - bb * 49) * 64;

    // B staging: phase q covers groups q*8..+8; 512 16B-chunks, 2/thread.
    const u16* bgp[2]; int bofs[2];
    #pragma unroll
    for (int i = 0; i < 2; ++i) {
        const int idx = i * 256 + tid;        // 0..511
        const int gg = idx >> 6, n = idx & 63;
        bgp[i]  = xc + (((size_t)bb * 96 + gg) * 3136 + hw0 + n) * 8;
        bofs[i] = idx * 8;
    }
    #define STAGE(q) { \
        u16* dst = Bsu + ((q) % 3) * 4096; \
        _Pragma("unroll") \
        for (int i = 0; i < 2; ++i) GLD16(bgp[i] + (size_t)(q) * 8 * 3136 * 8, dst + bofs[i]); }

    // A-fragment global pointers: row = mtile*192 + wv*48 + im*16 + l16
    const u16* arow[3];
    #pragma unroll
    for (int im = 0; im < 3; ++im)
        arow[im] = Wt + (size_t)(mtile * 192 + wv * 48 + im * 16 + l16) * 768 + quad * 8;

    f32x4 acc[3][4];
    #pragma unroll
    for (int im = 0; im < 3; ++im)
        #pragma unroll
        for (int in = 0; in < 4; ++in)
            acc[im][in] = {0.f, 0.f, 0.f, 0.f};

    #define COMPUTE(q) { \
        const u16* bufq = Bsu + ((q) % 3) * 4096; \
        _Pragma("unroll") \
        for (int s = 0; s < 2; ++s) { \
            const int k0 = (q) * 64 + s * 32; \
            short8 af[3], bfv[4]; \
            _Pragma("unroll") \
            for (int im = 0; im < 3; ++im) \
                af[im] = *(const short8*)(arow[im] + k0); \
            _Pragma("unroll") \
            for (int in = 0; in < 4; ++in) \
                bfv[in] = *(const short8*)(bufq + ((s * 4 + quad) * 64 + in * 16 + l16) * 8); \
            _Pragma("unroll") \
            for (int im = 0; im < 3; ++im) \
                _Pragma("unroll") \
                for (int in = 0; in < 4; ++in) \
                    acc[im][in] = __builtin_amdgcn_mfma_f32_16x16x32_bf16( \
                                      af[im], bfv[in], acc[im][in], 0, 0, 0); } }

    // Phase: stage 2 ahead; counted wait retires st(q) only; 2 raw barriers.
    #define PHASE(q, WAIT) { \
        if ((q) < 10) STAGE((q) + 2); \
        asm volatile(WAIT ::: "memory"); \
        __builtin_amdgcn_s_barrier(); \
        COMPUTE(q); \
        __builtin_amdgcn_s_barrier(); }

    STAGE(0);
    STAGE(1);
    PHASE(0,  "s_waitcnt vmcnt(4) lgkmcnt(0)");   // lgkm: PB writes visible
    PHASE(1,  "s_waitcnt vmcnt(4)");
    PHASE(2,  "s_waitcnt vmcnt(4)");
    PHASE(3,  "s_waitcnt vmcnt(4)");
    PHASE(4,  "s_waitcnt vmcnt(4)");
    PHASE(5,  "s_waitcnt vmcnt(4)");
    PHASE(6,  "s_waitcnt vmcnt(4)");
    PHASE(7,  "s_waitcnt vmcnt(4)");
    PHASE(8,  "s_waitcnt vmcnt(4)");
    PHASE(9,  "s_waitcnt vmcnt(4)");
    PHASE(10, "s_waitcnt vmcnt(2)");              // st(11) still in flight
    PHASE(11, "s_waitcnt vmcnt(0)");              // tail drain

    // --- epilogue: BN + exact GELU, per-wave LDS transpose, coalesced stores.
    // Entered after the final barrier: all staging retired, Bs free as T.
    float* T = (float*)smem + wv * (16 * 68);   // 4352 B/wave, disjoint
    const size_t obase = (size_t)bb * 384 * 3136 + hw0;
    #pragma unroll
    for (int im = 0; im < 3; ++im) {
        #pragma unroll
        for (int r = 0; r < 4; ++r) {
            const float2 sb = PB[(wv * 48 + im * 16 + quad * 4 + r)];
            #pragma unroll
            for (int in = 0; in < 4; ++in) {
                float v = acc[im][in][r] * sb.x + sb.y;
                v = 0.5f * v * (1.0f + erff(v * 0.70710678118654752f));
                T[(quad * 4 + r) * 68 + in * 16 + l16] = v;
            }
        }
        asm volatile("s_waitcnt lgkmcnt(0)" ::: "memory");
        #pragma unroll
        for (int it = 0; it < 4; ++it) {
            const int flat = it * 256 + lane * 4;   // 0..1023
            const int row = flat >> 6, col = flat & 63;
            const float4 vv = *(const float4*)&T[row * 68 + col];
            const size_t oi = obase +
                (size_t)(mtile * 192 + wv * 48 + im * 16 + row) * 3136 + col;
            if (fp) {
                *(float4*)((float*)outp + oi) = vv;
            } else {
                const u32 a = (u32)f2bf(vv.x) | ((u32)f2bf(vv.y) << 16);
                const u32 b2 = (u32)f2bf(vv.z) | ((u32)f2bf(vv.w) << 16);
                *(uint2*)((u16*)outp + oi) = make_uint2(a, b2);
            }
        }
        asm volatile("s_waitcnt lgkmcnt(0)" ::: "memory");
    }
    #undef PHASE
    #undef COMPUTE
    #undef STAGE
}

extern "C" void kernel_launch(void* const* d_in, const int* in_sizes, int n_in,
                              void* d_out, int out_size, void* d_ws, size_t ws_size,
                              hipStream_t stream) {
    const void* x   = d_in[0];
    const void* w   = d_in[1];
    const void* cbp = d_in[2];
    const void* bsc = d_in[3];
    const void* bbi = d_in[4];
    const void* bme = d_in[5];
    const void* bva = d_in[6];

    u16* xc   = (u16*)((char*)d_ws + 64);            // 77,070,336 B
    u16* wbf  = xc + (size_t)16 * 96 * 3136 * 8;     // 589,824 B

    prep_kernel<<<dim3(50, 16), 512, 0, stream>>>(x, w, xc, wbf);
    gemm_kernel<<<dim3(784, 2), 256, 0, stream>>>(xc, wbf, cbp, bsc, bbi, bme, bva,
                                                  d_out, x);
}